// Round 1
// baseline (92.740 us; speedup 1.0000x reference)
//
#include <hip/hip_runtime.h>

// Pooling_2D_density_3D: out[b,r,c] = sum_k mask[k,r]*mask[k,c]*X[b,cols[k,r],cols[k,c]]
// I=16, O=8, J=4, B=16 -> n_in=1024, n_out=256, K=81.
// Closed-form decomposition (derived from _build_projector_index, verified):
//   r = i1*32 + j1*4 + c1, c = i2*32 + j2*4 + c2
//   T0 (k=0, always):             X[row0+c1, col0+c2], row0=((2i1+1)*16+2j1+1)*4, col0=((2i2+1)*16+2j2+1)*4
//   T1 (k=1+8i+j, i1==i2&&j1==j2): X[rc+c1,   rc+c2],   rc  =(32*i1+2*j1)*4
//   T2 (k=65+i,  i1==i2):          X[row2+c1, col2+c2], row2=(32*i1+2*j1+1)*4,     col2=(32*i1+2*j2+1)*4
//   T3 (k=73+j,  j1==j2):          X[row3+c1, col3+c2], row3=((2i1+1)*16+2j1)*4,   col3=((2i2+1)*16+2j1)*4
//
// This version: one thread computes a full 4x4 output block (all c1 for its
// (b,i1,j1,i2,j2)). All c1-invariant work (index decode, di/dj, base addrs)
// amortizes 4x; the four T0 row-loads are independent -> 4-7 loads in flight
// per thread. Stores remain fully coalesced (lanes sweep g2 => contiguous
// 1 KiB per store instruction per c1).

__global__ __launch_bounds__(256) void pool_proj_kernel(const float* __restrict__ x,
                                                        float* __restrict__ out) {
    int q = blockIdx.x * blockDim.x + threadIdx.x;   // 0 .. 65535
    int b  = q >> 12;            // 16 batches (64*64 = 4096 threads per batch)
    int rg = (q >> 6) & 63;      // (i1,j1) output row-group
    int g2 = q & 63;             // (i2,j2) output col-group; c2 via float4
    int i2 = g2 >> 3, j2 = g2 & 7;
    int i1 = rg >> 3, j1 = rg & 7;

    const float* Xb = x + ((size_t)b << 20);         // 1024*1024 per batch

    // T0: always present
    int row0 = ((2 * i1 + 1) * 16 + (2 * j1 + 1)) * 4;
    int col0 = ((2 * i2 + 1) * 16 + (2 * j2 + 1)) * 4;
    const float* p0 = Xb + (size_t)row0 * 1024 + col0;
    float4 a0 = *(const float4*)(p0);
    float4 a1 = *(const float4*)(p0 + 1024);
    float4 a2 = *(const float4*)(p0 + 2048);
    float4 a3 = *(const float4*)(p0 + 3072);

    bool di = (i1 == i2);
    bool dj = (j1 == j2);

    if (di) {        // T2: k=65+i row-band projectors (4 consecutive rows)
        int row2 = (32 * i1 + 2 * j1 + 1) * 4;
        int col2 = (32 * i1 + 2 * j2 + 1) * 4;
        const float* p2 = Xb + (size_t)row2 * 1024 + col2;
        float4 v0 = *(const float4*)(p2);
        float4 v1 = *(const float4*)(p2 + 1024);
        float4 v2 = *(const float4*)(p2 + 2048);
        float4 v3 = *(const float4*)(p2 + 3072);
        a0.x += v0.x; a0.y += v0.y; a0.z += v0.z; a0.w += v0.w;
        a1.x += v1.x; a1.y += v1.y; a1.z += v1.z; a1.w += v1.w;
        a2.x += v2.x; a2.y += v2.y; a2.z += v2.z; a2.w += v2.w;
        a3.x += v3.x; a3.y += v3.y; a3.z += v3.z; a3.w += v3.w;
    }
    if (dj) {        // T3: k=73+j column-band projectors
        int row3 = ((2 * i1 + 1) * 16 + 2 * j1) * 4;
        int col3 = ((2 * i2 + 1) * 16 + 2 * j1) * 4;
        const float* p3 = Xb + (size_t)row3 * 1024 + col3;
        float4 v0 = *(const float4*)(p3);
        float4 v1 = *(const float4*)(p3 + 1024);
        float4 v2 = *(const float4*)(p3 + 2048);
        float4 v3 = *(const float4*)(p3 + 3072);
        a0.x += v0.x; a0.y += v0.y; a0.z += v0.z; a0.w += v0.w;
        a1.x += v1.x; a1.y += v1.y; a1.z += v1.z; a1.w += v1.w;
        a2.x += v2.x; a2.y += v2.y; a2.z += v2.z; a2.w += v2.w;
        a3.x += v3.x; a3.y += v3.y; a3.z += v3.z; a3.w += v3.w;
    }
    if (di && dj) {  // T1: 4x4 diagonal-block projectors k=1..64
        int rc = (32 * i1 + 2 * j1) * 4;
        const float* p1 = Xb + (size_t)rc * 1024 + rc;
        float4 v0 = *(const float4*)(p1);
        float4 v1 = *(const float4*)(p1 + 1024);
        float4 v2 = *(const float4*)(p1 + 2048);
        float4 v3 = *(const float4*)(p1 + 3072);
        a0.x += v0.x; a0.y += v0.y; a0.z += v0.z; a0.w += v0.w;
        a1.x += v1.x; a1.y += v1.y; a1.z += v1.z; a1.w += v1.w;
        a2.x += v2.x; a2.y += v2.y; a2.z += v2.z; a2.w += v2.w;
        a3.x += v3.x; a3.y += v3.y; a3.z += v3.z; a3.w += v3.w;
    }

    // out[b, rg*4 + c1, g2*4 .. g2*4+3] — lanes sweep g2 => each store
    // instruction writes a contiguous 1 KiB row of out.
    float* po = out + ((size_t)b << 16) + (size_t)(rg * 4) * 256 + g2 * 4;
    *(float4*)(po)       = a0;
    *(float4*)(po + 256) = a1;
    *(float4*)(po + 512) = a2;
    *(float4*)(po + 768) = a3;
}

extern "C" void kernel_launch(void* const* d_in, const int* in_sizes, int n_in,
                              void* d_out, int out_size, void* d_ws, size_t ws_size,
                              hipStream_t stream) {
    const float* x = (const float*)d_in[0];   // (16, 1024, 1024) fp32
    float* out = (float*)d_out;               // (16, 256, 256) fp32
    // 16*64*64 = 65536 threads, each computes a 4x4 output block
    dim3 grid(256), block(256);
    hipLaunchKernelGGL(pool_proj_kernel, grid, block, 0, stream, x, out);
}